// Round 11
// baseline (55.203 us; speedup 1.0000x reference)
//
#include <hip/hip_runtime.h>

// GHM-C loss, one-pass, register-only (R9 champion main + parallel final):
//   q = (c==t) ? -p : p ; e = exp(-|q|) ; bce = max(q,0) + ln(1+e)
//   cthr = #{|q| < ln9, ln4, ln(7/3), ln(3/2)} (monotone) ; bin = q>=0 ? 9-cthr : cthr
//   A_i = sum v gated by b_i ; B_i = sum (qp?v:-v) gated by b_i
//   PhiPre=(A+B)/2, PloPre=(A-B)/2; counts via ballot-mask popc (SALU).
//   ws is channel-major: ws[ch*stride + bid], ch in [0,21):
//   [0..4]=PhiPre [5..9]=PloPre [10]=sumw [11..15]=CntHiPre [16..20]=CntLoPre

#define NROWS 4194304

constexpr int BLOCK = 256;
constexpr int MAXGRID = 2048;
constexpr int STRD = MAXGRID * BLOCK; // 524288 -> exactly 8 rows/thread

#define GHM_DECL \
    float A0 = 0.f, A1 = 0.f, A2 = 0.f, A3 = 0.f, A4 = 0.f; \
    float B0 = 0.f, B1 = 0.f, B2 = 0.f, B3 = 0.f, B4 = 0.f; \
    unsigned cH0 = 0u, cH1 = 0u, cH2 = 0u, cH3 = 0u, cH4 = 0u; \
    unsigned cA1 = 0u, cA2 = 0u, cA3 = 0u, cA4 = 0u; \
    float sumw = 0.f;

#define GHM_ELEM(P, CI) { \
        const float q  = ((CI) == t) ? -(P) : (P); \
        const float aq = __builtin_fabsf(q); \
        const float e  = __builtin_amdgcn_exp2f(aq * NLOG2E); \
        const float l  = __builtin_amdgcn_logf(1.0f + e); \
        const float v  = fmaf(l, wln2, w * fmaxf(q, 0.0f)); \
        const bool qp = q >= 0.0f; \
        const bool b0 = aq < T0; \
        const bool b1 = aq < T1; \
        const bool b2 = aq < T2; \
        const bool b3 = aq < T3; \
        const float sv = qp ? v : -v; \
        const float m0 = b0 ? 1.0f : 0.0f; \
        const float m1 = b1 ? 1.0f : 0.0f; \
        const float m2 = b2 ? 1.0f : 0.0f; \
        const float m3 = b3 ? 1.0f : 0.0f; \
        A0 += v;  B0 += sv; \
        A1 = fmaf(v, m0, A1);  B1 = fmaf(sv, m0, B1); \
        A2 = fmaf(v, m1, A2);  B2 = fmaf(sv, m1, B2); \
        A3 = fmaf(v, m2, A3);  B3 = fmaf(sv, m2, B3); \
        A4 = fmaf(v, m3, A4);  B4 = fmaf(sv, m3, B4); \
        const unsigned long long Mq = __ballot(qp); \
        const unsigned long long M0 = __ballot(b0); \
        const unsigned long long M1 = __ballot(b1); \
        const unsigned long long M2 = __ballot(b2); \
        const unsigned long long M3 = __ballot(b3); \
        cH0 += (unsigned)__popcll(Mq); \
        cA1 += (unsigned)__popcll(M0);  cH1 += (unsigned)__popcll(Mq & M0); \
        cA2 += (unsigned)__popcll(M1);  cH2 += (unsigned)__popcll(Mq & M1); \
        cA3 += (unsigned)__popcll(M2);  cH3 += (unsigned)__popcll(Mq & M2); \
        cA4 += (unsigned)__popcll(M3);  cH4 += (unsigned)__popcll(Mq & M3); \
    }

#define GHM_ROW \
        sumw += w; \
        const float wln2 = w * LN2; \
        GHM_ELEM(a.x, 0) GHM_ELEM(a.y, 1) GHM_ELEM(a.z, 2) GHM_ELEM(a.w, 3) \
        GHM_ELEM(b.x, 4) GHM_ELEM(b.y, 5) GHM_ELEM(b.z, 6) GHM_ELEM(b.w, 7)

#define GHM_CONSTS \
    constexpr float NLOG2E = -1.4426950408889634f; \
    constexpr float LN2    = 0.6931471805599453f; \
    constexpr float T0 = 2.1972245773362196f; \
    constexpr float T1 = 1.3862943611198906f; \
    constexpr float T2 = 0.8472978603872037f; \
    constexpr float T3 = 0.4054651081081644f;

__device__ __forceinline__ void ghm_reduce_store(
    float A0, float A1, float A2, float A3, float A4,
    float B0, float B1, float B2, float B3, float B4,
    unsigned cA0, unsigned cA1, unsigned cA2, unsigned cA3, unsigned cA4,
    unsigned cH0, unsigned cH1, unsigned cH2, unsigned cH3, unsigned cH4,
    float sumw, float* __restrict__ ws, int wstride, int tid)
{
    float r11[11];
    r11[0] = 0.5f * (A0 + B0); r11[5] = 0.5f * (A0 - B0);
    r11[1] = 0.5f * (A1 + B1); r11[6] = 0.5f * (A1 - B1);
    r11[2] = 0.5f * (A2 + B2); r11[7] = 0.5f * (A2 - B2);
    r11[3] = 0.5f * (A3 + B3); r11[8] = 0.5f * (A3 - B3);
    r11[4] = 0.5f * (A4 + B4); r11[9] = 0.5f * (A4 - B4);
    r11[10] = sumw;

#pragma unroll
    for (int i = 0; i < 11; ++i) {
        float x = r11[i];
#pragma unroll
        for (int o = 32; o >= 1; o >>= 1) x += __shfl_xor(x, o, 64);
        r11[i] = x;
    }

    __shared__ float red4[4][21];
    const int lane = tid & 63, wv = tid >> 6;
    if (lane == 0) {
#pragma unroll
        for (int i = 0; i < 11; ++i) red4[wv][i] = r11[i];
        red4[wv][11] = (float)cH0;  red4[wv][16] = (float)(cA0 - cH0);
        red4[wv][12] = (float)cH1;  red4[wv][17] = (float)(cA1 - cH1);
        red4[wv][13] = (float)cH2;  red4[wv][18] = (float)(cA2 - cH2);
        red4[wv][14] = (float)cH3;  red4[wv][19] = (float)(cA3 - cH3);
        red4[wv][15] = (float)cH4;  red4[wv][20] = (float)(cA4 - cH4);
    }
    __syncthreads();
    if (tid < 21) {
        const float s = red4[0][tid] + red4[1][tid] + red4[2][tid] + red4[3][tid];
        // channel-major: ch = tid (0..20), contiguous per channel over blocks
        ws[(size_t)tid * (size_t)wstride + blockIdx.x] = s;
    }
}

// static kernel: grid == 2048 exactly, 8 rows/thread, guard-free
__global__ __launch_bounds__(BLOCK) void ghm_main_s(
    const float* __restrict__ pred, const int* __restrict__ target,
    const float* __restrict__ weight, float* __restrict__ ws, int wstride)
{
    __shared__ float wlds[8];
    const int tid = threadIdx.x;
    if (tid < 8) wlds[tid] = weight[tid];
    __syncthreads();

    GHM_DECL
    GHM_CONSTS
    const float4* __restrict__ p4 = reinterpret_cast<const float4*>(pred);
    const int r0 = blockIdx.x * BLOCK + tid;

#pragma unroll 2
    for (int k = 0; k < 8; ++k) {
        const int r = r0 + k * STRD;           // no bounds check: 8*STRD == NROWS
        const float4 a = p4[2 * (size_t)r];
        const float4 b = p4[2 * (size_t)r + 1];
        const int t = target[r];
        const float w = wlds[t];
        GHM_ROW
    }

    const unsigned cA0 = 8u * 512u; // 8 rows * 8 elems * 64 lanes, full waves
    ghm_reduce_store(A0, A1, A2, A3, A4, B0, B1, B2, B3, B4,
                     cA0, cA1, cA2, cA3, cA4, cH0, cH1, cH2, cH3, cH4,
                     sumw, ws, wstride, tid);
}

// dynamic fallback (any pow2 grid dividing NROWS)
__global__ __launch_bounds__(BLOCK) void ghm_main_d(
    const float* __restrict__ pred, const int* __restrict__ target,
    const float* __restrict__ weight, float* __restrict__ ws, int wstride)
{
    __shared__ float wlds[8];
    const int tid = threadIdx.x;
    if (tid < 8) wlds[tid] = weight[tid];
    __syncthreads();

    GHM_DECL
    GHM_CONSTS
    unsigned nrows = 0u;
    const int stride = gridDim.x * BLOCK;
    const float4* __restrict__ p4 = reinterpret_cast<const float4*>(pred);

    for (int r = blockIdx.x * BLOCK + tid; r < NROWS; r += stride) {
        const float4 a = p4[2 * (size_t)r];
        const float4 b = p4[2 * (size_t)r + 1];
        const int t = target[r];
        const float w = wlds[t];
        ++nrows;
        GHM_ROW
    }

    const unsigned cA0 = nrows * 512u;
    ghm_reduce_store(A0, A1, A2, A3, A4, B0, B1, B2, B3, B4,
                     cA0, cA1, cA2, cA3, cA4, cH0, cH1, cH2, cH3, cH4,
                     sumw, ws, wstride, tid);
}

// parallel final: 4 waves, each owns channels ch = wave + 4k; coalesced f4 reads
__global__ __launch_bounds__(BLOCK) void ghm_final(
    const float* __restrict__ ws, float* __restrict__ out, int nblocks, int wstride)
{
    __shared__ float U[21];
    const int tid = threadIdx.x;
    const int lane = tid & 63, wv = tid >> 6;

    for (int ch = wv; ch < 21; ch += 4) {
        float s = 0.f;
        const float* base = ws + (size_t)ch * (size_t)wstride;
        if (nblocks >= 4) {
            for (int idx = lane * 4; idx < nblocks; idx += 256) {
                const float4 u = *reinterpret_cast<const float4*>(base + idx);
                s += (u.x + u.y) + (u.z + u.w);
            }
        } else {
            for (int idx = lane; idx < nblocks; idx += 64) s += base[idx];
        }
#pragma unroll
        for (int o = 32; o >= 1; o >>= 1) s += __shfl_xor(s, o, 64);
        if (lane == 0) U[ch] = s;
    }
    __syncthreads();

    if (tid == 0) {
        float T[21];
#pragma unroll
        for (int i = 0; i < 10; ++i) T[i] = U[i];        // PhiPre/PloPre
#pragma unroll
        for (int k = 0; k < 5; ++k) {
            T[10 + k] = U[11 + k];                        // CntHiPre
            T[15 + k] = U[16 + k];                        // CntLoPre
        }
        T[20] = U[10];                                    // sumw

        float S[10], CN[10];
#pragma unroll
        for (int k = 0; k < 5; ++k) {
            const float shn = (k < 4) ? T[k + 1]      : 0.f;
            const float sln = (k < 4) ? T[5 + k + 1]  : 0.f;
            const float chn = (k < 4) ? T[10 + k + 1] : 0.f;
            const float cln = (k < 4) ? T[15 + k + 1] : 0.f;
            S[9 - k] = T[k]     - shn;  CN[9 - k] = T[10 + k] - chn;
            S[k]     = T[5 + k] - sln;  CN[k]     = T[15 + k] - cln;
        }
        int nne = 0; float acc = 0.f;
        const float tot = 33554432.0f; // N*C
#pragma unroll
        for (int i = 0; i < 10; ++i) {
            if (CN[i] > 0.5f) { nne++; acc += S[i] * (tot / CN[i]); }
        }
        out[0] = acc / (float)nne / (8.0f * T[20]);
    }
}

extern "C" void kernel_launch(void* const* d_in, const int* in_sizes, int n_in,
                              void* d_out, int out_size, void* d_ws, size_t ws_size,
                              hipStream_t stream) {
    const float* pred   = (const float*)d_in[0];
    const int*   target = (const int*)d_in[1];
    const float* weight = (const float*)d_in[2];
    float* out = (float*)d_out;

    int blocks;
    if (ws_size >= (size_t)21 * MAXGRID * 4u) {
        blocks = MAXGRID;
        ghm_main_s<<<MAXGRID, BLOCK, 0, stream>>>(pred, target, weight,
                                                  (float*)d_ws, MAXGRID);
    } else {
        const size_t cap = ws_size / (21u * 4u);
        blocks = 1;
        while ((size_t)blocks * 2 <= cap && blocks * 2 < MAXGRID) blocks *= 2;
        ghm_main_d<<<blocks, BLOCK, 0, stream>>>(pred, target, weight,
                                                 (float*)d_ws, blocks);
    }
    ghm_final<<<1, BLOCK, 0, stream>>>((const float*)d_ws, out, blocks, blocks);
}

// Round 12
// 46.973 us; speedup vs baseline: 1.1752x; 1.1752x over previous
//
#include <hip/hip_runtime.h>

// GHM-C loss, one-pass, register-only (R9 champion, restored verbatim):
//   q = (c==t) ? -p : p ; e = exp(-|q|) ; bce = max(q,0) + ln(1+e)
//   cthr = #{|q| < ln9, ln4, ln(7/3), ln(3/2)} (monotone) ; bin = q>=0 ? 9-cthr : cthr
//   A_i = sum v gated by b_i ; B_i = sum (qp?v:-v) gated by b_i
//   PhiPre=(A+B)/2, PloPre=(A-B)/2 at the end; counts via ballot-mask popc (SALU).
//   S[bin]/cnt[bin] reconstructed by differencing in ghm_final.

#define NROWS 4194304

constexpr int BLOCK = 256;
constexpr int MAXGRID = 2048;
constexpr int STRD = MAXGRID * BLOCK; // 524288 -> exactly 8 rows/thread

#define GHM_DECL \
    float A0 = 0.f, A1 = 0.f, A2 = 0.f, A3 = 0.f, A4 = 0.f; \
    float B0 = 0.f, B1 = 0.f, B2 = 0.f, B3 = 0.f, B4 = 0.f; \
    unsigned cH0 = 0u, cH1 = 0u, cH2 = 0u, cH3 = 0u, cH4 = 0u; \
    unsigned cA1 = 0u, cA2 = 0u, cA3 = 0u, cA4 = 0u; \
    float sumw = 0.f;

#define GHM_ELEM(P, CI) { \
        const float q  = ((CI) == t) ? -(P) : (P); \
        const float aq = __builtin_fabsf(q); \
        const float e  = __builtin_amdgcn_exp2f(aq * NLOG2E); \
        const float l  = __builtin_amdgcn_logf(1.0f + e); \
        const float v  = fmaf(l, wln2, w * fmaxf(q, 0.0f)); \
        const bool qp = q >= 0.0f; \
        const bool b0 = aq < T0; \
        const bool b1 = aq < T1; \
        const bool b2 = aq < T2; \
        const bool b3 = aq < T3; \
        const float sv = qp ? v : -v; \
        const float m0 = b0 ? 1.0f : 0.0f; \
        const float m1 = b1 ? 1.0f : 0.0f; \
        const float m2 = b2 ? 1.0f : 0.0f; \
        const float m3 = b3 ? 1.0f : 0.0f; \
        A0 += v;  B0 += sv; \
        A1 = fmaf(v, m0, A1);  B1 = fmaf(sv, m0, B1); \
        A2 = fmaf(v, m1, A2);  B2 = fmaf(sv, m1, B2); \
        A3 = fmaf(v, m2, A3);  B3 = fmaf(sv, m2, B3); \
        A4 = fmaf(v, m3, A4);  B4 = fmaf(sv, m3, B4); \
        const unsigned long long Mq = __ballot(qp); \
        const unsigned long long M0 = __ballot(b0); \
        const unsigned long long M1 = __ballot(b1); \
        const unsigned long long M2 = __ballot(b2); \
        const unsigned long long M3 = __ballot(b3); \
        cH0 += (unsigned)__popcll(Mq); \
        cA1 += (unsigned)__popcll(M0);  cH1 += (unsigned)__popcll(Mq & M0); \
        cA2 += (unsigned)__popcll(M1);  cH2 += (unsigned)__popcll(Mq & M1); \
        cA3 += (unsigned)__popcll(M2);  cH3 += (unsigned)__popcll(Mq & M2); \
        cA4 += (unsigned)__popcll(M3);  cH4 += (unsigned)__popcll(Mq & M3); \
    }

#define GHM_ROW \
        sumw += w; \
        const float wln2 = w * LN2; \
        GHM_ELEM(a.x, 0) GHM_ELEM(a.y, 1) GHM_ELEM(a.z, 2) GHM_ELEM(a.w, 3) \
        GHM_ELEM(b.x, 4) GHM_ELEM(b.y, 5) GHM_ELEM(b.z, 6) GHM_ELEM(b.w, 7)

#define GHM_CONSTS \
    constexpr float NLOG2E = -1.4426950408889634f; \
    constexpr float LN2    = 0.6931471805599453f; \
    constexpr float T0 = 2.1972245773362196f; \
    constexpr float T1 = 1.3862943611198906f; \
    constexpr float T2 = 0.8472978603872037f; \
    constexpr float T3 = 0.4054651081081644f;

__device__ __forceinline__ void ghm_reduce_store(
    float A0, float A1, float A2, float A3, float A4,
    float B0, float B1, float B2, float B3, float B4,
    unsigned cA0, unsigned cA1, unsigned cA2, unsigned cA3, unsigned cA4,
    unsigned cH0, unsigned cH1, unsigned cH2, unsigned cH3, unsigned cH4,
    float sumw, float* __restrict__ ws, int tid)
{
    float r11[11];
    r11[0] = 0.5f * (A0 + B0); r11[5] = 0.5f * (A0 - B0);
    r11[1] = 0.5f * (A1 + B1); r11[6] = 0.5f * (A1 - B1);
    r11[2] = 0.5f * (A2 + B2); r11[7] = 0.5f * (A2 - B2);
    r11[3] = 0.5f * (A3 + B3); r11[8] = 0.5f * (A3 - B3);
    r11[4] = 0.5f * (A4 + B4); r11[9] = 0.5f * (A4 - B4);
    r11[10] = sumw;

#pragma unroll
    for (int i = 0; i < 11; ++i) {
        float x = r11[i];
#pragma unroll
        for (int o = 32; o >= 1; o >>= 1) x += __shfl_xor(x, o, 64);
        r11[i] = x;
    }

    __shared__ float red4[4][21];
    const int lane = tid & 63, wv = tid >> 6;
    if (lane == 0) {
#pragma unroll
        for (int i = 0; i < 11; ++i) red4[wv][i] = r11[i];
        red4[wv][11] = (float)cH0;  red4[wv][16] = (float)(cA0 - cH0);
        red4[wv][12] = (float)cH1;  red4[wv][17] = (float)(cA1 - cH1);
        red4[wv][13] = (float)cH2;  red4[wv][18] = (float)(cA2 - cH2);
        red4[wv][14] = (float)cH3;  red4[wv][19] = (float)(cA3 - cH3);
        red4[wv][15] = (float)cH4;  red4[wv][20] = (float)(cA4 - cH4);
    }
    __syncthreads();
    if (tid < 21) {
        const float s = red4[0][tid] + red4[1][tid] + red4[2][tid] + red4[3][tid];
        // ws layout: [0..4]=PhiPre [5..9]=PloPre [10]=sumw [16..20]=CntHiPre [21..25]=CntLoPre
        const int slot = tid < 11 ? tid : tid + 5;
        ws[blockIdx.x * 32 + slot] = s;
    }
}

// static kernel: grid == 2048 exactly, 8 rows/thread, guard-free, compiler-scheduled
__global__ __launch_bounds__(BLOCK) void ghm_main_s(
    const float* __restrict__ pred, const int* __restrict__ target,
    const float* __restrict__ weight, float* __restrict__ ws)
{
    __shared__ float wlds[8];
    const int tid = threadIdx.x;
    if (tid < 8) wlds[tid] = weight[tid];
    __syncthreads();

    GHM_DECL
    GHM_CONSTS
    const float4* __restrict__ p4 = reinterpret_cast<const float4*>(pred);
    const int r0 = blockIdx.x * BLOCK + tid;

#pragma unroll 2
    for (int k = 0; k < 8; ++k) {
        const int r = r0 + k * STRD;           // no bounds check: 8*STRD == NROWS
        const float4 a = p4[2 * (size_t)r];
        const float4 b = p4[2 * (size_t)r + 1];
        const int t = target[r];
        const float w = wlds[t];
        GHM_ROW
    }

    const unsigned cA0 = 8u * 512u; // 8 rows * 8 elems * 64 lanes, full waves
    ghm_reduce_store(A0, A1, A2, A3, A4, B0, B1, B2, B3, B4,
                     cA0, cA1, cA2, cA3, cA4, cH0, cH1, cH2, cH3, cH4,
                     sumw, ws, tid);
}

// dynamic fallback (any pow2 grid dividing NROWS)
__global__ __launch_bounds__(BLOCK) void ghm_main_d(
    const float* __restrict__ pred, const int* __restrict__ target,
    const float* __restrict__ weight, float* __restrict__ ws)
{
    __shared__ float wlds[8];
    const int tid = threadIdx.x;
    if (tid < 8) wlds[tid] = weight[tid];
    __syncthreads();

    GHM_DECL
    GHM_CONSTS
    unsigned nrows = 0u;
    const int stride = gridDim.x * BLOCK;
    const float4* __restrict__ p4 = reinterpret_cast<const float4*>(pred);

    for (int r = blockIdx.x * BLOCK + tid; r < NROWS; r += stride) {
        const float4 a = p4[2 * (size_t)r];
        const float4 b = p4[2 * (size_t)r + 1];
        const int t = target[r];
        const float w = wlds[t];
        ++nrows;
        GHM_ROW
    }

    const unsigned cA0 = nrows * 512u;
    ghm_reduce_store(A0, A1, A2, A3, A4, B0, B1, B2, B3, B4,
                     cA0, cA1, cA2, cA3, cA4, cH0, cH1, cH2, cH3, cH4,
                     sumw, ws, tid);
}

__global__ __launch_bounds__(BLOCK) void ghm_final(
    const float* __restrict__ ws, float* __restrict__ out, int nblocks)
{
    float a21[21];
#pragma unroll
    for (int i = 0; i < 21; ++i) a21[i] = 0.f;

    for (int b = threadIdx.x; b < nblocks; b += BLOCK) {
#pragma unroll
        for (int i = 0; i < 10; ++i) a21[i] += ws[b * 32 + i];
#pragma unroll
        for (int i = 0; i < 10; ++i) a21[10 + i] += ws[b * 32 + 16 + i];
        a21[20] += ws[b * 32 + 10];
    }

#pragma unroll
    for (int i = 0; i < 21; ++i) {
        float x = a21[i];
#pragma unroll
        for (int o = 32; o >= 1; o >>= 1) x += __shfl_xor(x, o, 64);
        a21[i] = x;
    }

    __shared__ float red[4][21];
    const int tid = threadIdx.x;
    const int lane = tid & 63, wv = tid >> 6;
    if (lane == 0) {
#pragma unroll
        for (int i = 0; i < 21; ++i) red[wv][i] = a21[i];
    }
    __syncthreads();
    if (tid == 0) {
        float T[21];
#pragma unroll
        for (int i = 0; i < 21; ++i)
            T[i] = red[0][i] + red[1][i] + red[2][i] + red[3][i];
        // T[0..4]=PhiPre T[5..9]=PloPre T[10..14]=CntHiPre T[15..19]=CntLoPre T[20]=sumw
        float S[10], CN[10];
#pragma unroll
        for (int k = 0; k < 5; ++k) {
            const float shn = (k < 4) ? T[k + 1]      : 0.f;
            const float sln = (k < 4) ? T[5 + k + 1]  : 0.f;
            const float chn = (k < 4) ? T[10 + k + 1] : 0.f;
            const float cln = (k < 4) ? T[15 + k + 1] : 0.f;
            S[9 - k] = T[k]     - shn;  CN[9 - k] = T[10 + k] - chn;
            S[k]     = T[5 + k] - sln;  CN[k]     = T[15 + k] - cln;
        }
        int nne = 0; float acc = 0.f;
        const float tot = 33554432.0f; // N*C
#pragma unroll
        for (int i = 0; i < 10; ++i) {
            if (CN[i] > 0.5f) { nne++; acc += S[i] * (tot / CN[i]); }
        }
        out[0] = acc / (float)nne / (8.0f * T[20]);
    }
}

extern "C" void kernel_launch(void* const* d_in, const int* in_sizes, int n_in,
                              void* d_out, int out_size, void* d_ws, size_t ws_size,
                              hipStream_t stream) {
    const float* pred   = (const float*)d_in[0];
    const int*   target = (const int*)d_in[1];
    const float* weight = (const float*)d_in[2];
    float* out = (float*)d_out;

    int blocks;
    if (ws_size >= (size_t)MAXGRID * 128u) {
        blocks = MAXGRID;
        ghm_main_s<<<MAXGRID, BLOCK, 0, stream>>>(pred, target, weight, (float*)d_ws);
    } else {
        const int cap = (int)(ws_size / 128u);
        blocks = 1;
        while (blocks * 2 <= cap && blocks * 2 < MAXGRID) blocks *= 2; // pow2: exact divisibility
        ghm_main_d<<<blocks, BLOCK, 0, stream>>>(pred, target, weight, (float*)d_ws);
    }
    ghm_final<<<1, BLOCK, 0, stream>>>((const float*)d_ws, out, blocks);
}